// Round 1
// 7111.530 us; speedup vs baseline: 1.0727x; 1.0727x over previous
//
#include <hip/hip_runtime.h>

#define T_STEPS 4096
#define RSIZE   2048
#define N_IN    8
#define N_OUT   4
#define NWG     256
#define NT      256                  // 4 waves per WG
#define LIN_STRIDE  (RSIZE + N_IN)   // 2056 — readout weight row stride
#define SENTINEL    0x7FC00000u      // qNaN bits; recurrence never produces it

typedef float v4 __attribute__((ext_vector_type(4)));
typedef float v2 __attribute__((ext_vector_type(2)));

// d_ws: states [T][R] float. Row 0 zeros, rows 1.. sentinel. Data IS the flag.

__global__ __launch_bounds__(256) void init_kernel(v4* __restrict__ states4) {
    int idx = blockIdx.x * 256 + threadIdx.x;        // 0 .. T*R/4-1
    const float s = __uint_as_float(SENTINEL);
    v4 v = (idx < RSIZE / 4) ? (v4){0.f, 0.f, 0.f, 0.f} : (v4){s, s, s, s};
    states4[idx] = v;
}

__device__ __forceinline__ float dot4(v4 a, v4 b) {
    float s = a.x * b.x;
    s = fmaf(a.y, b.y, s);
    s = fmaf(a.z, b.z, s);
    s = fmaf(a.w, b.w, s);
    return s;
}

// LDS bank swizzle: element (v4 index) i lives at (i & ~127) | ((i&127) ^ ((i>>3)&7)).
// Involution; keeps every lane's column ownership identical (bit-exact math),
// but makes each consecutive 8-lane group hit all 8 bank-groups once.

__global__ __launch_bounds__(NT, 1) void reservoir_kernel(
    const float* __restrict__ W,        // [R][R]
    const float* __restrict__ Win,      // [R][8]
    const float* __restrict__ Wfb,      // [R][4]
    const float* __restrict__ inputs,   // [T][8]
    const float* __restrict__ outputs,  // [T][4]
    const float* __restrict__ noise,    // [T][R]
    float* __restrict__ states)         // [T][R]
{
    const int g    = blockIdx.x;
    const int t    = threadIdx.x;
    const int lane = t & 63;
    const int wv   = t >> 6;            // wave in WG: 0..3
    const int wid  = g * 4 + wv;        // global wave: 0..1023
    const int r0   = wid * 2;           // this wave's 2 rows

    // ---- W into NAMED registers: 2 rows x 32 cols/lane, cols = j*512 + lane*8 + k ----
    // (named scalars + asm pin: the previous array version was demoted by the
    //  compiler — VGPR_Count=56 < the 64 regs W needs — so W streamed from cache
    //  every step, on the critical path.)
    const float* wr0 = W + (size_t)r0 * RSIZE + lane * 8;
    const float* wr1 = wr0 + RSIZE;
    v4 w000 = *(const v4*)(wr0 +    0), w001 = *(const v4*)(wr0 +    4);
    v4 w010 = *(const v4*)(wr0 +  512), w011 = *(const v4*)(wr0 +  516);
    v4 w020 = *(const v4*)(wr0 + 1024), w021 = *(const v4*)(wr0 + 1028);
    v4 w030 = *(const v4*)(wr0 + 1536), w031 = *(const v4*)(wr0 + 1540);
    v4 w100 = *(const v4*)(wr1 +    0), w101 = *(const v4*)(wr1 +    4);
    v4 w110 = *(const v4*)(wr1 +  512), w111 = *(const v4*)(wr1 +  516);
    v4 w120 = *(const v4*)(wr1 + 1024), w121 = *(const v4*)(wr1 + 1028);
    v4 w130 = *(const v4*)(wr1 + 1536), w131 = *(const v4*)(wr1 + 1540);
    // Pin W in VGPRs: opaque to the optimizer, so it cannot sink/rematerialize
    // the loads into the time loop or push the values to scratch.
    asm volatile("" : "+v"(w000), "+v"(w001), "+v"(w010), "+v"(w011));
    asm volatile("" : "+v"(w020), "+v"(w021), "+v"(w030), "+v"(w031));
    asm volatile("" : "+v"(w100), "+v"(w101), "+v"(w110), "+v"(w111));
    asm volatile("" : "+v"(w120), "+v"(w121), "+v"(w130), "+v"(w131));

    // ---- lanes 0,1 keep Win/Wfb for their row ----
    float win[N_IN] = {0}, wfb[N_OUT] = {0};
    if (lane < 2) {
        const int r = r0 + lane;
        #pragma unroll
        for (int j = 0; j < N_IN; ++j)  win[j] = Win[r * N_IN + j];
        #pragma unroll
        for (int k = 0; k < N_OUT; ++k) wfb[k] = Wfb[r * N_OUT + k];
    }

    // parity double-buffered x in LDS (bank-swizzled)
    __shared__ v4 xsh[2][RSIZE / 4];    // 16 KB
    const int e     = lane * 2;                  // v4-pair base within a 128-v4 block
    const int sx    = e ^ ((e >> 3) & 7);        // swizzled position (sx^1 = partner)
    const int fillc = wv * 512 + lane * 8;       // col this lane polls/fills
    const int fbase = wv * 128;                  // v4-index base of this wave's block

    for (int n = 1; n < T_STEPS; ++n) {
        // ---- pre-poll: terms that don't depend on x_{n-1} ----
        float pre = 0.0f, nz = 0.0f;
        if (lane < 2) {
            const int r = r0 + lane;
            nz = noise[(size_t)n * RSIZE + r];
            #pragma unroll
            for (int j = 0; j < N_IN; ++j)  pre = fmaf(win[j], inputs[n * N_IN + j], pre);
            #pragma unroll
            for (int k = 0; k < N_OUT; ++k) pre = fmaf(wfb[k], outputs[(n - 1) * N_OUT + k], pre);
        }

        // ---- poll my 8 contiguous cols of x_{n-1} (2x volatile dwordx4) ----
        const volatile v4* src =
            (const volatile v4*)(states + (size_t)(n - 1) * RSIZE + fillc);
        v4 a, b;
        for (;;) {
            a = src[0];
            b = src[1];
            bool ok = (__float_as_uint(a.x) != SENTINEL) &
                      (__float_as_uint(a.y) != SENTINEL) &
                      (__float_as_uint(a.z) != SENTINEL) &
                      (__float_as_uint(a.w) != SENTINEL) &
                      (__float_as_uint(b.x) != SENTINEL) &
                      (__float_as_uint(b.y) != SENTINEL) &
                      (__float_as_uint(b.z) != SENTINEL) &
                      (__float_as_uint(b.w) != SENTINEL);
            if (ok) break;
            __builtin_amdgcn_s_sleep(1);
        }

        const int p = (n - 1) & 1;
        xsh[p][fbase + sx]       = a;    // swizzled, conflict-free ds_write_b128
        xsh[p][fbase + (sx ^ 1)] = b;
        __syncthreads();

        // ---- 2-row dot over all 2048 cols from LDS (same columns/order as before) ----
        float acc0 = 0.0f, acc1 = 0.0f;
        {
            v4 x0 = xsh[p][  0 + sx], x1 = xsh[p][  0 + (sx ^ 1)];
            acc0 += dot4(w000, x0) + dot4(w001, x1);
            acc1 += dot4(w100, x0) + dot4(w101, x1);
        }
        {
            v4 x0 = xsh[p][128 + sx], x1 = xsh[p][128 + (sx ^ 1)];
            acc0 += dot4(w010, x0) + dot4(w011, x1);
            acc1 += dot4(w110, x0) + dot4(w111, x1);
        }
        {
            v4 x0 = xsh[p][256 + sx], x1 = xsh[p][256 + (sx ^ 1)];
            acc0 += dot4(w020, x0) + dot4(w021, x1);
            acc1 += dot4(w120, x0) + dot4(w121, x1);
        }
        {
            v4 x0 = xsh[p][384 + sx], x1 = xsh[p][384 + (sx ^ 1)];
            acc0 += dot4(w030, x0) + dot4(w031, x1);
            acc1 += dot4(w130, x0) + dot4(w131, x1);
        }

        // ---- 64-lane butterfly: every lane ends with both row totals ----
        #pragma unroll
        for (int m = 1; m < 64; m <<= 1) {
            acc0 += __shfl_xor(acc0, m, 64);
            acc1 += __shfl_xor(acc1, m, 64);
        }

        // ---- epilogue + publish: lanes 0,1 compute, lane 0 stores 8B once ----
        float xn = 0.0f;
        if (lane < 2) {
            float s = (lane == 0 ? acc0 : acc1) + pre;
            xn = tanhf(s) + nz;
        }
        float xn1 = __shfl(xn, 1, 64);
        if (lane == 0) {
            v2 st; st.x = xn; st.y = xn1;
            *(volatile v2*)(states + (size_t)n * RSIZE + r0) = st;
        }
        __builtin_amdgcn_s_waitcnt(0);   // flush publish promptly
    }
}

__global__ __launch_bounds__(256) void readout_kernel(
    const float* __restrict__ states,   // [T][R]
    const float* __restrict__ inputs,   // [T][8]
    const float* __restrict__ lin_w,    // [4][2056]
    const float* __restrict__ lin_b,    // [4]
    float* __restrict__ out)            // [T][4]
{
    const int ti   = blockIdx.x;
    const int tid  = threadIdx.x;
    const int lane = tid & 63;
    const int wave = tid >> 6;
    const int c0   = tid * 8;

    const float* xp = states + (size_t)ti * RSIZE + c0;
    v4 xa = *(const v4*)xp;
    v4 xb = *(const v4*)(xp + 4);

    float acc[N_OUT];
    #pragma unroll
    for (int o = 0; o < N_OUT; ++o) {
        const float* lp = lin_w + (size_t)o * LIN_STRIDE + c0;
        v4 la = *(const v4*)lp;
        v4 lb = *(const v4*)(lp + 4);
        acc[o] = dot4(la, xa) + dot4(lb, xb);
    }

    #pragma unroll
    for (int m = 1; m < 64; m <<= 1) {
        #pragma unroll
        for (int o = 0; o < N_OUT; ++o) acc[o] += __shfl_xor(acc[o], m, 64);
    }

    __shared__ float red[4][N_OUT];
    if (lane == 0) {
        #pragma unroll
        for (int o = 0; o < N_OUT; ++o) red[wave][o] = acc[o];
    }
    __syncthreads();

    if (tid < N_OUT) {
        float s = red[0][tid] + red[1][tid] + red[2][tid] + red[3][tid] + lin_b[tid];
        if (ti > 0) {   // states_u row 0 is zero
            #pragma unroll
            for (int j = 0; j < N_IN; ++j)
                s = fmaf(lin_w[(size_t)tid * LIN_STRIDE + RSIZE + j],
                         inputs[ti * N_IN + j], s);
        }
        out[ti * N_OUT + tid] = s;
    }
}

extern "C" void kernel_launch(void* const* d_in, const int* in_sizes, int n_in,
                              void* d_out, int out_size, void* d_ws, size_t ws_size,
                              hipStream_t stream) {
    const float* inputs  = (const float*)d_in[0];
    const float* outputs = (const float*)d_in[1];
    const float* W       = (const float*)d_in[2];
    const float* Win     = (const float*)d_in[3];
    const float* Wfb     = (const float*)d_in[4];
    const float* lin_w   = (const float*)d_in[5];
    const float* lin_b   = (const float*)d_in[6];
    const float* noise   = (const float*)d_in[7];
    float* out = (float*)d_out;

    float* states = (float*)d_ws;

    hipLaunchKernelGGL(init_kernel, dim3((T_STEPS * RSIZE / 4) / 256), dim3(256), 0,
                       stream, (v4*)states);
    hipLaunchKernelGGL(reservoir_kernel, dim3(NWG), dim3(NT), 0, stream,
                       W, Win, Wfb, inputs, outputs, noise, states);
    hipLaunchKernelGGL(readout_kernel, dim3(T_STEPS), dim3(256), 0, stream,
                       states, inputs, lin_w, lin_b, out);
}